// Round 2
// baseline (21667.940 us; speedup 1.0000x reference)
//
#include <hip/hip_runtime.h>
#include <math.h>

#define DEV __device__ __forceinline__

// Problem sizes: V=32000 E=512 HID=1024 L=2 NH=8 B=4 T=128 M=512 S=1024 MH=4
// DH=128 TOPK=32 INTERVAL=16 DECAY=0.99 BT=128 SH=4 SD=128

// ---------------- workspace layout (float offsets), ~50.5 MB total ----------
constexpr size_t OFF_MEM    = 0;              // 4*1024*512
constexpr size_t OFF_RV     = 2097152;        // 2 buffers x 2048 (ping-pong)
constexpr size_t OFF_BAR    = 2101248;        // barrier counter (uint at [0])
constexpr size_t OFF_STATS  = 2101312;        // 16 bh * 8 {kth,max,invse}x2
constexpr size_t OFF_KEYINV = 2101440;        // [2][16]
constexpr size_t OFF_IFACE  = 2101504;        // 4*2049 (padded 8448)
constexpr size_t OFF_SIMR   = 2109952;        // 16*1024
constexpr size_t OFF_SIMW   = 2126336;        // 16*1024
constexpr size_t OFF_RSEQ   = 2142720;        // 4*128*512
constexpr size_t OFF_HS     = 2404864;        // 4*128*512
constexpr size_t OFF_PREIF  = 2667008;        // 4*128*2049 (pad to 1049600)
constexpr size_t OFF_CTRL   = 3716608;        // 512*1024
constexpr size_t OFF_RPART  = 3716608;        // aliased with CTRL (disjoint in time)
constexpr size_t OFF_BUFA   = 4240896;        // 4096*512
constexpr size_t OFF_BUFB   = 6338048;        // 4096*512
constexpr size_t OFF_BUFC   = 8435200;        // 4096*512
constexpr size_t OFF_BUFD   = 10532352;       // 4096*512

DEV float gelu_f(float x) {
  float x3 = x * x * x;
  return 0.5f * x * (1.f + tanhf(0.7978845608028654f * (x + 0.044715f * x3)));
}
DEV float sigm_f(float x) { return 1.f / (1.f + expf(-x)); }

DEV float wave_sum(float v) {
#pragma unroll
  for (int m = 32; m >= 1; m >>= 1) v += __shfl_xor(v, m, 64);
  return v;
}
DEV float wave_max(float v) {
#pragma unroll
  for (int m = 32; m >= 1; m >>= 1) v = fmaxf(v, __shfl_xor(v, m, 64));
  return v;
}

// ---------------- embed + pos ----------------
__global__ void __launch_bounds__(256) k_embed(const int* __restrict__ tok,
                                               const float* __restrict__ emb,
                                               const float* __restrict__ pos,
                                               float* __restrict__ x) {
  int bt = blockIdx.x;          // 0..511
  int t = bt & 127;
  int tid = threadIdx.x;
  int tk = tok[bt];
  x[(size_t)bt * 512 + tid]       = emb[(size_t)tk * 512 + tid] + pos[(size_t)t * 512 + tid];
  x[(size_t)bt * 512 + 256 + tid] = emb[(size_t)tk * 512 + 256 + tid] + pos[(size_t)t * 512 + 256 + tid];
}

// ---------------- layernorm over 512 (one block per row) ----------------
__global__ void __launch_bounds__(256) k_ln(const float* __restrict__ x,
                                            float* __restrict__ y) {
  int row = blockIdx.x;
  int tid = threadIdx.x;
  __shared__ float w4[4];
  const float* xr = x + (size_t)row * 512;
  float a = xr[tid], b2 = xr[tid + 256];
  float s = wave_sum(a + b2);
  int lane = tid & 63, w = tid >> 6;
  if (lane == 0) w4[w] = s;
  __syncthreads();
  float mu = (w4[0] + w4[1] + w4[2] + w4[3]) * (1.f / 512.f);
  __syncthreads();
  float da = a - mu, db = b2 - mu;
  float vs = wave_sum(da * da + db * db);
  if (lane == 0) w4[w] = vs;
  __syncthreads();
  float var = (w4[0] + w4[1] + w4[2] + w4[3]) * (1.f / 512.f);
  float inv = 1.f / sqrtf(var + 1e-5f);
  y[(size_t)row * 512 + tid] = da * inv;
  y[(size_t)row * 512 + 256 + tid] = db * inv;
}

// ---------------- generic fp32 GEMM: C[M,N] = op(A[M,K] @ B[K,N]) ----------
// 64x64 tile, KT=32, 256 threads, 4x4 per thread.
template <int BIAS, int GELU, int RES, int GUARD>
__global__ void __launch_bounds__(256) k_gemm(const float* __restrict__ A,
                                              const float* __restrict__ Bm,
                                              const float* __restrict__ bias,
                                              float* __restrict__ C,
                                              int Mr, int Nr, int Kr) {
  __shared__ float As[32][68];
  __shared__ float Bs[32][68];
  int n0 = blockIdx.x * 64, m0 = blockIdx.y * 64;
  int tid = threadIdx.x;
  int tx = tid & 15, ty = tid >> 4;
  float acc[4][4] = {};
  for (int k0 = 0; k0 < Kr; k0 += 32) {
#pragma unroll
    for (int p = 0; p < 2; p++) {
      int i4 = tid + p * 256;
      int r = i4 >> 3, kk = (i4 & 7) * 4;
      const float4 av = *(const float4*)(A + (size_t)(m0 + r) * Kr + k0 + kk);
      As[kk + 0][r] = av.x; As[kk + 1][r] = av.y;
      As[kk + 2][r] = av.z; As[kk + 3][r] = av.w;
    }
#pragma unroll
    for (int p = 0; p < 2; p++) {
      int i4 = tid + p * 256;
      int r = i4 >> 4, nn = (i4 & 15) * 4;
      float4 bv;
      if (!GUARD) {
        bv = *(const float4*)(Bm + (size_t)(k0 + r) * Nr + n0 + nn);
      } else {
        int nb2 = n0 + nn;
        const float* brow = Bm + (size_t)(k0 + r) * Nr;
        bv.x = (nb2 + 0 < Nr) ? brow[nb2 + 0] : 0.f;
        bv.y = (nb2 + 1 < Nr) ? brow[nb2 + 1] : 0.f;
        bv.z = (nb2 + 2 < Nr) ? brow[nb2 + 2] : 0.f;
        bv.w = (nb2 + 3 < Nr) ? brow[nb2 + 3] : 0.f;
      }
      *(float4*)&Bs[r][nn] = bv;
    }
    __syncthreads();
#pragma unroll
    for (int kk = 0; kk < 32; kk++) {
      float av[4], bv[4];
      *(float4*)av = *(const float4*)&As[kk][ty * 4];
      *(float4*)bv = *(const float4*)&Bs[kk][tx * 4];
#pragma unroll
      for (int i = 0; i < 4; i++)
#pragma unroll
        for (int j = 0; j < 4; j++) acc[i][j] = fmaf(av[i], bv[j], acc[i][j]);
    }
    __syncthreads();
  }
#pragma unroll
  for (int i = 0; i < 4; i++) {
    int m = m0 + ty * 4 + i;
#pragma unroll
    for (int j = 0; j < 4; j++) {
      int n = n0 + tx * 4 + j;
      if (GUARD && n >= Nr) continue;
      float v = acc[i][j];
      if (BIAS) v += bias[n];
      if (GELU) v = gelu_f(v);
      size_t idx = (size_t)m * Nr + n;
      if (RES) v += C[idx];
      C[idx] = v;
    }
  }
}

// ---------------- transformer attention (causal, hd=64, T=128) -------------
__global__ void __launch_bounds__(128) k_attn(const float* __restrict__ qkv,
                                              float* __restrict__ out) {
  int blk = blockIdx.x;         // 4096 = B*NH*T
  int q = blk & 127, h = (blk >> 7) & 7, b = blk >> 10;
  int tid = threadIdx.x;
  __shared__ float qv[64];
  __shared__ float sc[128];
  __shared__ float rb[2];
  if (tid < 64) qv[tid] = qkv[(size_t)(b * 128 + q) * 1536 + h * 64 + tid];
  __syncthreads();
  float s = -INFINITY;
  if (tid <= q) {
    const float* kr = qkv + (size_t)(b * 128 + tid) * 1536 + 512 + h * 64;
    float d0 = 0, d1 = 0;
    for (int e = 0; e < 64; e += 2) {
      d0 = fmaf(qv[e], kr[e], d0);
      d1 = fmaf(qv[e + 1], kr[e + 1], d1);
    }
    s = (d0 + d1) * 0.125f;
  }
  float m_ = wave_max(s);
  if ((tid & 63) == 0) rb[tid >> 6] = m_;
  __syncthreads();
  float mx = fmaxf(rb[0], rb[1]);
  __syncthreads();
  float p = (tid <= q) ? expf(s - mx) : 0.f;
  sc[tid] = p;
  float ss = wave_sum(p);
  if ((tid & 63) == 0) rb[tid >> 6] = ss;
  __syncthreads();
  float denom = rb[0] + rb[1];
  if (tid < 64) {
    float o = 0;
    for (int j = 0; j <= q; j++)
      o = fmaf(sc[j], qkv[(size_t)(b * 128 + j) * 1536 + 1024 + h * 64 + tid], o);
    out[(size_t)(b * 128 + q) * 512 + h * 64 + tid] = o / denom;
  }
}

// ---------------- synthesize attention (flash, S=1024, SD=128, full) -------
#define SCALE_S 0.08838834764831845f
__global__ void __launch_bounds__(256) k_sattn(const float* __restrict__ Qg,
                                               const float* __restrict__ Kg,
                                               const float* __restrict__ Vg,
                                               float* __restrict__ Og) {
  int blk = blockIdx.x;           // 512 = b*4h*32qb
  int qb = blk & 31, h = (blk >> 5) & 3, b = blk >> 7;
  int tid = threadIdx.x;
  __shared__ float Qs[32][132];
  __shared__ float Ks[64][132];
  __shared__ float Ps[32][68];
  __shared__ float redm[32][17];
  __shared__ float mrow[32], lrow[32], arow[32];

  size_t qbase = ((size_t)(b * 1024 + qb * 32)) * 512 + (size_t)h * 128;
#pragma unroll
  for (int p = 0; p < 4; p++) {
    int i4 = tid + p * 256;
    int r = i4 >> 5, dv = (i4 & 31) * 4;
    *(float4*)&Qs[r][dv] = *(const float4*)(Qg + qbase + (size_t)r * 512 + dv);
  }
  if (tid < 32) { mrow[tid] = -INFINITY; lrow[tid] = 0.f; }
  float Oacc[16] = {};
  int qo = tid >> 3, db = tid & 7;
  int qg = tid & 15, jgq = tid >> 4, j0 = jgq * 4;
  __syncthreads();

  for (int kc = 0; kc < 16; kc++) {
    size_t kbase = ((size_t)(b * 1024 + kc * 64)) * 512 + (size_t)h * 128;
#pragma unroll
    for (int p = 0; p < 8; p++) {
      int i4 = tid + p * 256;
      int r = i4 >> 5, dv = (i4 & 31) * 4;
      *(float4*)&Ks[r][dv] = *(const float4*)(Kg + kbase + (size_t)r * 512 + dv);
    }
    __syncthreads();
    float a0[4] = {}, a1[4] = {};
#pragma unroll 4
    for (int d = 0; d < 128; d++) {
      float qa = Qs[qg][d], qb2 = Qs[qg + 16][d];
#pragma unroll
      for (int jj = 0; jj < 4; jj++) {
        float kv = Ks[j0 + jj][d];
        a0[jj] = fmaf(qa, kv, a0[jj]);
        a1[jj] = fmaf(qb2, kv, a1[jj]);
      }
    }
    float mx0 = -INFINITY, mx1 = -INFINITY;
#pragma unroll
    for (int jj = 0; jj < 4; jj++) {
      a0[jj] *= SCALE_S; a1[jj] *= SCALE_S;
      mx0 = fmaxf(mx0, a0[jj]); mx1 = fmaxf(mx1, a1[jj]);
    }
    redm[qg][jgq] = mx0; redm[qg + 16][jgq] = mx1;
    __syncthreads();
    if (tid < 32) {
      float cm = redm[tid][0];
#pragma unroll
      for (int i = 1; i < 16; i++) cm = fmaxf(cm, redm[tid][i]);
      float mo = mrow[tid], mn = fmaxf(mo, cm);
      arow[tid] = expf(mo - mn);
      mrow[tid] = mn;
    }
    __syncthreads();
    float mn0 = mrow[qg], mn1 = mrow[qg + 16];
    float ps0 = 0, ps1 = 0;
#pragma unroll
    for (int jj = 0; jj < 4; jj++) {
      float p0 = expf(a0[jj] - mn0); Ps[qg][j0 + jj] = p0; ps0 += p0;
      float p1 = expf(a1[jj] - mn1); Ps[qg + 16][j0 + jj] = p1; ps1 += p1;
    }
    redm[qg][jgq] = ps0; redm[qg + 16][jgq] = ps1;
    __syncthreads();
    if (tid < 32) {
      float cs = 0;
#pragma unroll
      for (int i = 0; i < 16; i++) cs += redm[tid][i];
      lrow[tid] = lrow[tid] * arow[tid] + cs;
    }
    // load V into Ks (K reads done)
    {
      size_t vbase = ((size_t)(b * 1024 + kc * 64)) * 512 + (size_t)h * 128;
#pragma unroll
      for (int p = 0; p < 8; p++) {
        int i4 = tid + p * 256;
        int r = i4 >> 5, dv = (i4 & 31) * 4;
        *(float4*)&Ks[r][dv] = *(const float4*)(Vg + vbase + (size_t)r * 512 + dv);
      }
    }
    __syncthreads();
    float al = arow[qo];
#pragma unroll
    for (int u = 0; u < 16; u++) Oacc[u] *= al;
    for (int j = 0; j < 64; j++) {
      float p = Ps[qo][j];
#pragma unroll
      for (int u = 0; u < 4; u++) {
        const float4 v4 = *(const float4*)&Ks[j][db * 4 + u * 32];
        Oacc[u * 4 + 0] = fmaf(p, v4.x, Oacc[u * 4 + 0]);
        Oacc[u * 4 + 1] = fmaf(p, v4.y, Oacc[u * 4 + 1]);
        Oacc[u * 4 + 2] = fmaf(p, v4.z, Oacc[u * 4 + 2]);
        Oacc[u * 4 + 3] = fmaf(p, v4.w, Oacc[u * 4 + 3]);
      }
    }
    __syncthreads();
  }
  float invl = 1.f / lrow[qo];
  size_t obase = ((size_t)(b * 1024 + qb * 32 + qo)) * 512 + (size_t)h * 128 + db * 4;
#pragma unroll
  for (int u = 0; u < 4; u++) {
    float4 o4;
    o4.x = Oacc[u * 4 + 0] * invl; o4.y = Oacc[u * 4 + 1] * invl;
    o4.z = Oacc[u * 4 + 2] * invl; o4.w = Oacc[u * 4 + 3] * invl;
    *(float4*)(Og + obase + u * 32) = o4;
  }
}

// ---------------- cooperative scan kernel ----------------
struct ScanArgs {
  float* ws;
  const float* Wif;
  const float* betar;
  const float* betaw;
  int t0, t1;
};

// Grid barrier: arrive with one release-RMW, spin with acquire LOADS (not
// RMWs). Round-1 RMW-spin serialized 128 blocks' RMWs on one line at the
// coherence point (~15us/barrier); load-spin broadcasts from LLC.
DEV void gsync(unsigned* bar, int* c, int nb) {
  __syncthreads();
  if (threadIdx.x == 0) {
    unsigned tgt = (unsigned)(++(*c)) * (unsigned)nb;
    __threadfence();
    __hip_atomic_fetch_add(bar, 1u, __ATOMIC_RELEASE, __HIP_MEMORY_SCOPE_AGENT);
    while (__hip_atomic_load(bar, __ATOMIC_ACQUIRE, __HIP_MEMORY_SCOPE_AGENT) < tgt)
      __builtin_amdgcn_s_sleep(2);
    __threadfence();
  }
  __syncthreads();
}

__global__ void __launch_bounds__(256) k_scan(ScanArgs a) {
  float* ws = a.ws;
  float* mem = ws + OFF_MEM;
  float* rv = ws + OFF_RV;        // [2][4][512] ping-pong by t&1
  unsigned* bar = (unsigned*)(ws + OFF_BAR);
  float* stats = ws + OFF_STATS;
  float* keyinv = ws + OFF_KEYINV;
  float* ifc = ws + OFF_IFACE;
  float* simr = ws + OFF_SIMR;
  float* simw = ws + OFF_SIMW;
  float* rseq = ws + OFF_RSEQ;
  float* rpart = ws + OFF_RPART;  // [4][32][512] per-subblock read partials
  const float* preif = ws + OFF_PREIF;

  const int tid = threadIdx.x;
  const int blk = blockIdx.x;
  const int nb = gridDim.x;     // 128
  const int b = blk >> 5;
  const int sub = blk & 31;

  __shared__ float sbuf[1024];
  __shared__ float rvs[512];
  __shared__ unsigned hist[256];
  __shared__ unsigned scanb[256];
  __shared__ unsigned sh_pref;
  __shared__ int sh_k;
  __shared__ float rbuf[4];

  int bcnt = 4 * a.t0;          // global barrier count continues across segments

  float beta_r = fminf(fmaxf(log1pf(expf(a.betar[0])), 1.f), 20.f);
  float beta_w = fminf(fmaxf(log1pf(expf(a.betaw[0])), 1.f), 20.f);

  for (int t = a.t0; t < a.t1; ++t) {
    // ---------------- Phase A: rv reduce, iface = preif + rv @ Wif[512:] ----
    if (sub < 9) {
      // deterministic read_vec: rv_old(parity t) + sum of step-(t-1) partials
      const float* rvold = rv + ((t & 1) ? 2048 : 0) + (b << 9);
      const float* rp = rpart + (size_t)b * 32 * 512;
#pragma unroll
      for (int p = 0; p < 2; p++) {
        int i = tid + p * 256;
        float v = rvold[i];
        for (int s2 = 0; s2 < 32; s2++) v += rp[s2 * 512 + i];
        rvs[i] = v;
      }
      __syncthreads();
      if (sub == 0) {
        float* rvnew = rv + ((t & 1) ? 0 : 2048) + (b << 9);
#pragma unroll
        for (int p = 0; p < 2; p++) {
          int i = tid + p * 256;
          rvnew[i] = rvs[i];
          if (t > 0) rseq[((size_t)b * 128 + (t - 1)) * 512 + i] = rvs[i];
        }
      }
      int j = sub * 256 + tid;
      if (j < 2049) {
        float val = preif[((size_t)b * 128 + t) * 2049 + j];
        const float* wp = a.Wif + (size_t)512 * 2049 + j;
        float v0 = 0, v1 = 0, v2 = 0, v3 = 0;
        for (int k = 0; k < 512; k += 4) {
          v0 = fmaf(rvs[k + 0], wp[(size_t)(k + 0) * 2049], v0);
          v1 = fmaf(rvs[k + 1], wp[(size_t)(k + 1) * 2049], v1);
          v2 = fmaf(rvs[k + 2], wp[(size_t)(k + 2) * 2049], v2);
          v3 = fmaf(rvs[k + 3], wp[(size_t)(k + 3) * 2049], v3);
        }
        val += (v0 + v1) + (v2 + v3);
        float o = val;
        if (j >= 1536) o = sigm_f(val);   // erase region + add-gate
        ifc[b * 2049 + j] = o;
        if (sub < 4) {                    // key norms (rk: sub 0,1; wk: sub 2,3)
          float v2s = wave_sum(val * val);
          int lane = tid & 63, w = tid >> 6;
          if (lane == 0) sbuf[w] = v2s;
          __syncthreads();
          if (tid == 0) {
            float g0 = sbuf[0] + sbuf[1], g1 = sbuf[2] + sbuf[3];
            int rw = sub >> 1, hh = (sub & 1) * 2;
            keyinv[rw * 16 + b * 4 + hh] = 1.f / sqrtf(g0 + 1e-8f);
            keyinv[rw * 16 + b * 4 + hh + 1] = 1.f / sqrtf(g1 + 1e-8f);
          }
        }
      }
    }
    gsync(bar, &bcnt, nb);

    // ---------------- Phase B: sims (cosine * beta) -------------------------
#pragma unroll
    for (int p = 0; p < 4; p++) sbuf[tid + p * 256] = ifc[b * 2049 + tid + p * 256];
    __syncthreads();
    {
      int lane = tid & 63, w = tid >> 6;
      int s0 = ((sub << 2) + w) * 8;
      int h = lane >> 4, u8 = (lane & 15) * 8;
      float rkv[8], wkv[8];
#pragma unroll
      for (int i = 0; i < 8; i++) {
        rkv[i] = sbuf[h * 128 + u8 + i];
        wkv[i] = sbuf[512 + h * 128 + u8 + i];
      }
      float kir = keyinv[b * 4 + h] * beta_r;
      float kiw = keyinv[16 + b * 4 + h] * beta_w;
      for (int sl = 0; sl < 8; sl++) {
        int s = s0 + sl;
        const float4* mp = (const float4*)(mem + ((size_t)b * 1024 + s) * 512 + h * 128 + u8);
        float4 va = mp[0], vb = mp[1];
        float mv[8] = {va.x, va.y, va.z, va.w, vb.x, vb.y, vb.z, vb.w};
        float ssq = 0, dr = 0, dw = 0;
#pragma unroll
        for (int i = 0; i < 8; i++) {
          ssq = fmaf(mv[i], mv[i], ssq);
          dr = fmaf(mv[i], rkv[i], dr);
          dw = fmaf(mv[i], wkv[i], dw);
        }
#pragma unroll
        for (int msk = 1; msk < 16; msk <<= 1) {
          ssq += __shfl_xor(ssq, msk, 64);
          dr += __shfl_xor(dr, msk, 64);
          dw += __shfl_xor(dw, msk, 64);
        }
        if ((lane & 15) == 0) {
          float invs = 1.f / sqrtf(ssq + 1e-8f);
          simr[((size_t)(b * 4 + h)) * 1024 + s] = dr * invs * kir;
          simw[((size_t)(b * 4 + h)) * 1024 + s] = dw * invs * kiw;
        }
      }
    }
    gsync(bar, &bcnt, nb);

    // ---------------- Phase C: exact 32nd-largest + softmax stats -----------
    if (blk < 32) {
      int sel = blk >> 4, bh = blk & 15;
      const float* sim = (sel ? simw : simr) + (size_t)bh * 1024;
      float f0[4]; unsigned u[4];
#pragma unroll
      for (int i = 0; i < 4; i++) {
        f0[i] = sim[tid * 4 + i];
        unsigned bb = __float_as_uint(f0[i]);
        u[i] = (bb & 0x80000000u) ? ~bb : (bb | 0x80000000u);
      }
      float mx = fmaxf(fmaxf(f0[0], f0[1]), fmaxf(f0[2], f0[3]));
      mx = wave_max(mx);
      if ((tid & 63) == 0) rbuf[tid >> 6] = mx;
      if (tid == 0) { sh_pref = 0u; sh_k = 32; }
      __syncthreads();
      float maxv = fmaxf(fmaxf(rbuf[0], rbuf[1]), fmaxf(rbuf[2], rbuf[3]));
      __syncthreads();
      for (int pass = 0; pass < 4; pass++) {
        int shift = 24 - pass * 8;
        hist[tid] = 0u;
        __syncthreads();
        unsigned pref = sh_pref; int kk = sh_k;
        unsigned pm = (pass == 0) ? 0u : (0xFFFFFFFFu << (shift + 8));
#pragma unroll
        for (int i = 0; i < 4; i++)
          if ((u[i] & pm) == pref) atomicAdd(&hist[(u[i] >> shift) & 255], 1u);
        __syncthreads();
        scanb[tid] = hist[tid];
        __syncthreads();
        for (int off = 1; off < 256; off <<= 1) {
          unsigned addv = (tid + off < 256) ? scanb[tid + off] : 0u;
          __syncthreads();
          scanb[tid] += addv;
          __syncthreads();
        }
        unsigned ge = scanb[tid];
        unsigned gt = (tid < 255) ? scanb[tid + 1] : 0u;
        if (ge >= (unsigned)kk && gt < (unsigned)kk) {
          sh_pref = pref | ((unsigned)tid << shift);
          sh_k = kk - (int)gt;
        }
        __syncthreads();
      }
      unsigned ku = sh_pref;
      float kth = __uint_as_float((ku & 0x80000000u) ? (ku & 0x7FFFFFFFu) : ~ku);
      float se = 0.f;
#pragma unroll
      for (int i = 0; i < 4; i++)
        if (f0[i] >= kth) se += expf(f0[i] - maxv);
      se = wave_sum(se);
      if ((tid & 63) == 0) rbuf[tid >> 6] = se;
      __syncthreads();
      if (tid == 0) {
        float tot = rbuf[0] + rbuf[1] + rbuf[2] + rbuf[3];
        float* st = stats + bh * 8 + sel * 4;
        st[0] = kth; st[1] = maxv; st[2] = 1.f / tot;
      }
    }
    gsync(bar, &bcnt, nb);

    // ---------------- Phase D: read-partials + mem update -------------------
    {
      int sc0 = sub * 32;
      int h0 = tid >> 7;
      int bh0 = b * 4 + h0, bh1 = bh0 + 2;
      float ag = ifc[b * 2049 + 2048];
      float wv0 = ifc[b * 2049 + 1024 + tid];
      float wv1 = ifc[b * 2049 + 1024 + 256 + tid];
      float er0 = ifc[b * 2049 + 1536 + tid];
      float er1 = ifc[b * 2049 + 1536 + 256 + tid];
      const float* st0 = stats + bh0 * 8;
      const float* st1 = stats + bh1 * 8;
      float kr0 = st0[0], mr0 = st0[1], ir0 = st0[2];
      float kw0 = st0[4], mw0 = st0[5], iw0 = st0[6];
      float kr1 = st1[0], mr1 = st1[1], ir1 = st1[2];
      float kw1 = st1[4], mw1 = st1[5], iw1 = st1[6];
      float racc0 = 0.f, racc1 = 0.f;
      for (int sl = 0; sl < 32; sl++) {
        int s = sc0 + sl;
        float sr0 = simr[(size_t)bh0 * 1024 + s], sw0 = simw[(size_t)bh0 * 1024 + s];
        float sr1 = simr[(size_t)bh1 * 1024 + s], sw1 = simw[(size_t)bh1 * 1024 + s];
        float wr0 = (sr0 >= kr0) ? expf(sr0 - mr0) * ir0 : 0.f;
        float ww0 = (sw0 >= kw0) ? expf(sw0 - mw0) * iw0 : 0.f;
        float wr1 = (sr1 >= kr1) ? expf(sr1 - mr1) * ir1 : 0.f;
        float ww1 = (sw1 >= kw1) ? expf(sw1 - mw1) * iw1 : 0.f;
        size_t base = ((size_t)b * 1024 + s) * 512;
        float old0 = mem[base + tid];
        float old1 = mem[base + 256 + tid];
        racc0 = fmaf(wr0, old0, racc0);
        racc1 = fmaf(wr1, old1, racc1);
        mem[base + tid]       = (old0 * (1.f - ww0 * er0) + ag * ww0 * wv0) * 0.99f;
        mem[base + 256 + tid] = (old1 * (1.f - ww1 * er1) + ag * ww1 * wv1) * 0.99f;
      }
      float* rp = rpart + ((size_t)b * 32 + sub) * 512;
      rp[tid] = racc0;
      rp[tid + 256] = racc1;
    }
    gsync(bar, &bcnt, nb);
  }
  // final read_vec snapshot (only meaningful at the very end of the scan)
  if (a.t1 == 128 && sub == 0) {
    const float* rvold = rv + ((a.t1 & 1) ? 2048 : 0) + (b << 9);
    const float* rp = rpart + (size_t)b * 32 * 512;
#pragma unroll
    for (int p = 0; p < 2; p++) {
      int i = tid + p * 256;
      float v = rvold[i];
      for (int s2 = 0; s2 < 32; s2++) v += rp[s2 * 512 + i];
      rseq[((size_t)b * 128 + 127) * 512 + i] = v;
    }
  }
}

// ---------------- concat [hs, rseq] -> ctrl ----------------
__global__ void __launch_bounds__(256) k_concat(const float* __restrict__ hs,
                                                const float* __restrict__ rs,
                                                float* __restrict__ ctrl) {
  int bt = blockIdx.x;
  int tid = threadIdx.x;
#pragma unroll
  for (int p = 0; p < 4; p++) {
    int i = tid + p * 256;
    ctrl[(size_t)bt * 1024 + i] =
        (i < 512) ? hs[(size_t)bt * 512 + i] : rs[(size_t)bt * 512 + (i - 512)];
  }
}

// ---------------- host ----------------
extern "C" void kernel_launch(void* const* d_in, const int* in_sizes, int n_in,
                              void* d_out, int out_size, void* d_ws, size_t ws_size,
                              hipStream_t stream) {
  (void)in_sizes; (void)n_in; (void)out_size; (void)ws_size;
  const int* tok = (const int*)d_in[0];
  const float* emb = (const float*)d_in[1];
  const float* pos = (const float*)d_in[2];
  const float* Wqkv = (const float*)d_in[3];
  const float* Wo = (const float*)d_in[4];
  const float* W1 = (const float*)d_in[5];
  const float* W2 = (const float*)d_in[6];
  const float* Wif = (const float*)d_in[7];
  const float* bif = (const float*)d_in[8];
  const float* Wlg = (const float*)d_in[9];
  const float* br = (const float*)d_in[10];
  const float* bw = (const float*)d_in[11];
  const float* Whall = (const float*)d_in[12];
  const float* bhall = (const float*)d_in[13];
  const float* Sq = (const float*)d_in[14];
  const float* Sk = (const float*)d_in[15];
  const float* Sv = (const float*)d_in[16];
  const float* So = (const float*)d_in[17];
  const float* SW1 = (const float*)d_in[18];
  const float* SW2 = (const float*)d_in[19];
  float* ws = (float*)d_ws;
  float* out = (float*)d_out;

  float* mem = ws + OFF_MEM;
  float* rseq = ws + OFF_RSEQ;
  float* hs = ws + OFF_HS;
  float* preif = ws + OFF_PREIF;
  float* ctrl = ws + OFF_CTRL;
  float* bufA = ws + OFF_BUFA;
  float* bufB = ws + OFF_BUFB;
  float* bufC = ws + OFF_BUFC;
  float* bufD = ws + OFF_BUFD;

  // zero mem, read_vec (both buffers), barrier counter; and rpart (step-0 read)
  hipMemsetAsync(d_ws, 0, (OFF_BAR + 64) * sizeof(float), stream);
  hipMemsetAsync(ws + OFF_RPART, 0, 65536 * sizeof(float), stream);

  // ---- transformer ----
  k_embed<<<512, 256, 0, stream>>>(tok, emb, pos, hs);
  for (int l = 0; l < 2; l++) {
    k_ln<<<512, 256, 0, stream>>>(hs, bufA);
    k_gemm<0, 0, 0, 0><<<dim3(24, 8), 256, 0, stream>>>(
        bufA, Wqkv + (size_t)l * 512 * 1536, nullptr, bufB, 512, 1536, 512);
    k_attn<<<4096, 128, 0, stream>>>(bufB, bufC);
    k_gemm<0, 0, 1, 0><<<dim3(8, 8), 256, 0, stream>>>(
        bufC, Wo + (size_t)l * 512 * 512, nullptr, hs, 512, 512, 512);
    k_ln<<<512, 256, 0, stream>>>(hs, bufA);
    k_gemm<0, 1, 0, 0><<<dim3(16, 8), 256, 0, stream>>>(
        bufA, W1 + (size_t)l * 512 * 1024, nullptr, bufB, 512, 1024, 512);
    k_gemm<0, 0, 1, 0><<<dim3(8, 8), 256, 0, stream>>>(
        bufB, W2 + (size_t)l * 1024 * 512, nullptr, hs, 512, 512, 1024);
  }
  // pre_iface = hs @ Wif[:512] + b_iface
  k_gemm<1, 0, 0, 1><<<dim3(33, 8), 256, 0, stream>>>(hs, Wif, bif, preif, 512, 2049, 512);

  // ---- scan: 9 cooperative segments, synthesize after first 8 ----
  const int segs[10] = {0, 1, 17, 33, 49, 65, 81, 97, 113, 128};
  for (int sgi = 0; sgi < 9; sgi++) {
    ScanArgs sa{ws, Wif, br, bw, segs[sgi], segs[sgi + 1]};
    void* kp[] = {&sa};
    hipLaunchCooperativeKernel((void*)k_scan, dim3(128), dim3(256), kp, 0, stream);
    if (sgi < 8) {
      k_ln<<<4096, 256, 0, stream>>>(mem, bufA);
      k_gemm<0, 0, 0, 0><<<dim3(8, 64), 256, 0, stream>>>(bufA, Sq, nullptr, bufB, 4096, 512, 512);
      k_gemm<0, 0, 0, 0><<<dim3(8, 64), 256, 0, stream>>>(bufA, Sk, nullptr, bufC, 4096, 512, 512);
      k_gemm<0, 0, 0, 0><<<dim3(8, 64), 256, 0, stream>>>(bufA, Sv, nullptr, bufD, 4096, 512, 512);
      k_sattn<<<512, 256, 0, stream>>>(bufB, bufC, bufD, bufA);
      k_gemm<0, 0, 1, 0><<<dim3(8, 64), 256, 0, stream>>>(bufA, So, nullptr, mem, 4096, 512, 512);
      k_ln<<<4096, 256, 0, stream>>>(mem, bufA);
      k_gemm<0, 1, 0, 0><<<dim3(2, 64), 256, 0, stream>>>(bufA, SW1, nullptr, bufB, 4096, 128, 512);
      k_gemm<0, 0, 1, 0><<<dim3(8, 64), 256, 0, stream>>>(bufB, SW2, nullptr, mem, 4096, 512, 128);
    }
  }

  // ---- deferred outputs ----
  k_concat<<<512, 256, 0, stream>>>(hs, rseq, ctrl);
  k_gemm<0, 0, 0, 0><<<dim3(500, 8), 256, 0, stream>>>(ctrl, Wlg, nullptr, out, 512, 32000, 1024);
  k_gemm<1, 0, 0, 0><<<dim3(8, 8), 256, 0, stream>>>(
      rseq, Whall, bhall, out + (size_t)512 * 32000, 512, 512, 512);
}

// Round 3
// 10747.249 us; speedup vs baseline: 2.0161x; 2.0161x over previous
//
#include <hip/hip_runtime.h>
#include <math.h>

#define DEV __device__ __forceinline__

// Problem sizes: V=32000 E=512 HID=1024 L=2 NH=8 B=4 T=128 M=512 S=1024 MH=4
// DH=128 TOPK=32 INTERVAL=16 DECAY=0.99 BT=128 SH=4 SD=128

// ---------------- workspace layout (float offsets), ~48.5 MB ----------------
constexpr size_t OFF_MEM    = 0;              // 4*1024*512
constexpr size_t OFF_SYNC   = 2097152;        // 2304: BCTR[4]x64 | GC2[16]x64 | GC3[16]x64
constexpr size_t OFF_RVBUF  = 2099456;        // 2 x 4*512 ping-pong
constexpr size_t OFF_RPART  = 2103552;        // 2 x [4][4][4][128] parity
constexpr size_t OFF_KEYINV = 2119936;        // [2][16]
constexpr size_t OFF_IFACE  = 2120000;        // 4 x 2176 (stride-padded 2049)
constexpr size_t OFF_SIMR   = 2128704;        // 16*1024
constexpr size_t OFF_SIMW   = 2145088;        // 16*1024
constexpr size_t OFF_RSEQ   = 2161472;        // RVA: 4*128*512 (rv_after(t))
constexpr size_t OFF_HS     = 2423616;        // 4*128*512
constexpr size_t OFF_PREIF  = 2685760;        // 4*128*2049
constexpr size_t OFF_BUFA   = 3734848;        // 4096*512 (also ctrl 512*1024 later)
constexpr size_t OFF_BUFB   = 5832000;
constexpr size_t OFF_BUFC   = 7929152;
constexpr size_t OFF_BUFD   = 10026304;       // end 12123456 floats

DEV float gelu_f(float x) {
  float x3 = x * x * x;
  return 0.5f * x * (1.f + tanhf(0.7978845608028654f * (x + 0.044715f * x3)));
}
DEV float sigm_f(float x) { return 1.f / (1.f + expf(-x)); }

DEV float wave_sum(float v) {
#pragma unroll
  for (int m = 32; m >= 1; m >>= 1) v += __shfl_xor(v, m, 64);
  return v;
}
DEV float wave_max(float v) {
#pragma unroll
  for (int m = 32; m >= 1; m >>= 1) v = fmaxf(v, __shfl_xor(v, m, 64));
  return v;
}

// ---------------- embed + pos ----------------
__global__ void __launch_bounds__(256) k_embed(const int* __restrict__ tok,
                                               const float* __restrict__ emb,
                                               const float* __restrict__ pos,
                                               float* __restrict__ x) {
  int bt = blockIdx.x;
  int t = bt & 127;
  int tid = threadIdx.x;
  int tk = tok[bt];
  x[(size_t)bt * 512 + tid]       = emb[(size_t)tk * 512 + tid] + pos[(size_t)t * 512 + tid];
  x[(size_t)bt * 512 + 256 + tid] = emb[(size_t)tk * 512 + 256 + tid] + pos[(size_t)t * 512 + 256 + tid];
}

// ---------------- layernorm over 512 ----------------
__global__ void __launch_bounds__(256) k_ln(const float* __restrict__ x,
                                            float* __restrict__ y) {
  int row = blockIdx.x;
  int tid = threadIdx.x;
  __shared__ float w4[4];
  const float* xr = x + (size_t)row * 512;
  float a = xr[tid], b2 = xr[tid + 256];
  float s = wave_sum(a + b2);
  int lane = tid & 63, w = tid >> 6;
  if (lane == 0) w4[w] = s;
  __syncthreads();
  float mu = (w4[0] + w4[1] + w4[2] + w4[3]) * (1.f / 512.f);
  __syncthreads();
  float da = a - mu, db = b2 - mu;
  float vs = wave_sum(da * da + db * db);
  if (lane == 0) w4[w] = vs;
  __syncthreads();
  float var = (w4[0] + w4[1] + w4[2] + w4[3]) * (1.f / 512.f);
  float inv = 1.f / sqrtf(var + 1e-5f);
  y[(size_t)row * 512 + tid] = da * inv;
  y[(size_t)row * 512 + 256 + tid] = db * inv;
}

// ---------------- generic fp32 GEMM: 64x64 tile, KT=32 ----------------
template <int BIAS, int GELU, int RES, int GUARD>
__global__ void __launch_bounds__(256) k_gemm(const float* __restrict__ A,
                                              const float* __restrict__ Bm,
                                              const float* __restrict__ bias,
                                              float* __restrict__ C,
                                              int Mr, int Nr, int Kr) {
  __shared__ float As[32][68];
  __shared__ float Bs[32][68];
  int n0 = blockIdx.x * 64, m0 = blockIdx.y * 64;
  int tid = threadIdx.x;
  int tx = tid & 15, ty = tid >> 4;
  float acc[4][4] = {};
  for (int k0 = 0; k0 < Kr; k0 += 32) {
#pragma unroll
    for (int p = 0; p < 2; p++) {
      int i4 = tid + p * 256;
      int r = i4 >> 3, kk = (i4 & 7) * 4;
      const float4 av = *(const float4*)(A + (size_t)(m0 + r) * Kr + k0 + kk);
      As[kk + 0][r] = av.x; As[kk + 1][r] = av.y;
      As[kk + 2][r] = av.z; As[kk + 3][r] = av.w;
    }
#pragma unroll
    for (int p = 0; p < 2; p++) {
      int i4 = tid + p * 256;
      int r = i4 >> 4, nn = (i4 & 15) * 4;
      float4 bv;
      if (!GUARD) {
        bv = *(const float4*)(Bm + (size_t)(k0 + r) * Nr + n0 + nn);
      } else {
        int nb2 = n0 + nn;
        const float* brow = Bm + (size_t)(k0 + r) * Nr;
        bv.x = (nb2 + 0 < Nr) ? brow[nb2 + 0] : 0.f;
        bv.y = (nb2 + 1 < Nr) ? brow[nb2 + 1] : 0.f;
        bv.z = (nb2 + 2 < Nr) ? brow[nb2 + 2] : 0.f;
        bv.w = (nb2 + 3 < Nr) ? brow[nb2 + 3] : 0.f;
      }
      *(float4*)&Bs[r][nn] = bv;
    }
    __syncthreads();
#pragma unroll
    for (int kk = 0; kk < 32; kk++) {
      float av[4], bv[4];
      *(float4*)av = *(const float4*)&As[kk][ty * 4];
      *(float4*)bv = *(const float4*)&Bs[kk][tx * 4];
#pragma unroll
      for (int i = 0; i < 4; i++)
#pragma unroll
        for (int j = 0; j < 4; j++) acc[i][j] = fmaf(av[i], bv[j], acc[i][j]);
    }
    __syncthreads();
  }
#pragma unroll
  for (int i = 0; i < 4; i++) {
    int m = m0 + ty * 4 + i;
#pragma unroll
    for (int j = 0; j < 4; j++) {
      int n = n0 + tx * 4 + j;
      if (GUARD && n >= Nr) continue;
      float v = acc[i][j];
      if (BIAS) v += bias[n];
      if (GELU) v = gelu_f(v);
      size_t idx = (size_t)m * Nr + n;
      if (RES) v += C[idx];
      C[idx] = v;
    }
  }
}

// ---------------- transformer attention (causal, hd=64, T=128) -------------
__global__ void __launch_bounds__(128) k_attn(const float* __restrict__ qkv,
                                              float* __restrict__ out) {
  int blk = blockIdx.x;
  int q = blk & 127, h = (blk >> 7) & 7, b = blk >> 10;
  int tid = threadIdx.x;
  __shared__ float qv[64];
  __shared__ float sc[128];
  __shared__ float rb[2];
  if (tid < 64) qv[tid] = qkv[(size_t)(b * 128 + q) * 1536 + h * 64 + tid];
  __syncthreads();
  float s = -INFINITY;
  if (tid <= q) {
    const float* kr = qkv + (size_t)(b * 128 + tid) * 1536 + 512 + h * 64;
    float d0 = 0, d1 = 0;
    for (int e = 0; e < 64; e += 2) {
      d0 = fmaf(qv[e], kr[e], d0);
      d1 = fmaf(qv[e + 1], kr[e + 1], d1);
    }
    s = (d0 + d1) * 0.125f;
  }
  float m_ = wave_max(s);
  if ((tid & 63) == 0) rb[tid >> 6] = m_;
  __syncthreads();
  float mx = fmaxf(rb[0], rb[1]);
  __syncthreads();
  float p = (tid <= q) ? expf(s - mx) : 0.f;
  sc[tid] = p;
  float ss = wave_sum(p);
  if ((tid & 63) == 0) rb[tid >> 6] = ss;
  __syncthreads();
  float denom = rb[0] + rb[1];
  if (tid < 64) {
    float o = 0;
    for (int j = 0; j <= q; j++)
      o = fmaf(sc[j], qkv[(size_t)(b * 128 + j) * 1536 + 1024 + h * 64 + tid], o);
    out[(size_t)(b * 128 + q) * 512 + h * 64 + tid] = o / denom;
  }
}

// ---------------- synthesize attention (flash, S=1024, SD=128) -------------
#define SCALE_S 0.08838834764831845f
__global__ void __launch_bounds__(256) k_sattn(const float* __restrict__ Qg,
                                               const float* __restrict__ Kg,
                                               const float* __restrict__ Vg,
                                               float* __restrict__ Og) {
  int blk = blockIdx.x;
  int qb = blk & 31, h = (blk >> 5) & 3, b = blk >> 7;
  int tid = threadIdx.x;
  __shared__ float Qs[32][132];
  __shared__ float Ks[64][132];
  __shared__ float Ps[32][68];
  __shared__ float redm[32][17];
  __shared__ float mrow[32], lrow[32], arow[32];

  size_t qbase = ((size_t)(b * 1024 + qb * 32)) * 512 + (size_t)h * 128;
#pragma unroll
  for (int p = 0; p < 4; p++) {
    int i4 = tid + p * 256;
    int r = i4 >> 5, dv = (i4 & 31) * 4;
    *(float4*)&Qs[r][dv] = *(const float4*)(Qg + qbase + (size_t)r * 512 + dv);
  }
  if (tid < 32) { mrow[tid] = -INFINITY; lrow[tid] = 0.f; }
  float Oacc[16] = {};
  int qo = tid >> 3, db = tid & 7;
  int qg = tid & 15, jgq = tid >> 4, j0 = jgq * 4;
  __syncthreads();

  for (int kc = 0; kc < 16; kc++) {
    size_t kbase = ((size_t)(b * 1024 + kc * 64)) * 512 + (size_t)h * 128;
#pragma unroll
    for (int p = 0; p < 8; p++) {
      int i4 = tid + p * 256;
      int r = i4 >> 5, dv = (i4 & 31) * 4;
      *(float4*)&Ks[r][dv] = *(const float4*)(Kg + kbase + (size_t)r * 512 + dv);
    }
    __syncthreads();
    float a0[4] = {}, a1[4] = {};
#pragma unroll 4
    for (int d = 0; d < 128; d++) {
      float qa = Qs[qg][d], qb2 = Qs[qg + 16][d];
#pragma unroll
      for (int jj = 0; jj < 4; jj++) {
        float kv = Ks[j0 + jj][d];
        a0[jj] = fmaf(qa, kv, a0[jj]);
        a1[jj] = fmaf(qb2, kv, a1[jj]);
      }
    }
    float mx0 = -INFINITY, mx1 = -INFINITY;
#pragma unroll
    for (int jj = 0; jj < 4; jj++) {
      a0[jj] *= SCALE_S; a1[jj] *= SCALE_S;
      mx0 = fmaxf(mx0, a0[jj]); mx1 = fmaxf(mx1, a1[jj]);
    }
    redm[qg][jgq] = mx0; redm[qg + 16][jgq] = mx1;
    __syncthreads();
    if (tid < 32) {
      float cm = redm[tid][0];
#pragma unroll
      for (int i = 1; i < 16; i++) cm = fmaxf(cm, redm[tid][i]);
      float mo = mrow[tid], mn = fmaxf(mo, cm);
      arow[tid] = expf(mo - mn);
      mrow[tid] = mn;
    }
    __syncthreads();
    float mn0 = mrow[qg], mn1 = mrow[qg + 16];
    float ps0 = 0, ps1 = 0;
#pragma unroll
    for (int jj = 0; jj < 4; jj++) {
      float p0 = expf(a0[jj] - mn0); Ps[qg][j0 + jj] = p0; ps0 += p0;
      float p1 = expf(a1[jj] - mn1); Ps[qg + 16][j0 + jj] = p1; ps1 += p1;
    }
    redm[qg][jgq] = ps0; redm[qg + 16][jgq] = ps1;
    __syncthreads();
    if (tid < 32) {
      float cs = 0;
#pragma unroll
      for (int i = 0; i < 16; i++) cs += redm[tid][i];
      lrow[tid] = lrow[tid] * arow[tid] + cs;
    }
    {
      size_t vbase = ((size_t)(b * 1024 + kc * 64)) * 512 + (size_t)h * 128;
#pragma unroll
      for (int p = 0; p < 8; p++) {
        int i4 = tid + p * 256;
        int r = i4 >> 5, dv = (i4 & 31) * 4;
        *(float4*)&Ks[r][dv] = *(const float4*)(Vg + vbase + (size_t)r * 512 + dv);
      }
    }
    __syncthreads();
    float al = arow[qo];
#pragma unroll
    for (int u = 0; u < 16; u++) Oacc[u] *= al;
    for (int j = 0; j < 64; j++) {
      float p = Ps[qo][j];
#pragma unroll
      for (int u = 0; u < 4; u++) {
        const float4 v4 = *(const float4*)&Ks[j][db * 4 + u * 32];
        Oacc[u * 4 + 0] = fmaf(p, v4.x, Oacc[u * 4 + 0]);
        Oacc[u * 4 + 1] = fmaf(p, v4.y, Oacc[u * 4 + 1]);
        Oacc[u * 4 + 2] = fmaf(p, v4.z, Oacc[u * 4 + 2]);
        Oacc[u * 4 + 3] = fmaf(p, v4.w, Oacc[u * 4 + 3]);
      }
    }
    __syncthreads();
  }
  float invl = 1.f / lrow[qo];
  size_t obase = ((size_t)(b * 1024 + qb * 32 + qo)) * 512 + (size_t)h * 128 + db * 4;
#pragma unroll
  for (int u = 0; u < 4; u++) {
    float4 o4;
    o4.x = Oacc[u * 4 + 0] * invl; o4.y = Oacc[u * 4 + 1] * invl;
    o4.z = Oacc[u * 4 + 2] * invl; o4.w = Oacc[u * 4 + 3] * invl;
    *(float4*)(Og + obase + u * 32) = o4;
  }
}

// ---------------- cooperative scan kernel (64 blocks = 4b x 4h x 4g) --------
struct ScanArgs {
  float* ws;
  const float* Wif;
  const float* betar;
  const float* betaw;
  int t0, t1, sgi;
};

// Relaxed RMW-spin barrier (round-2 lesson: NEVER acquire-load spin on gfx950;
// round-1 lesson: keep spinners-per-line low -> <=16 arrivals per counter).
DEV void barrier_at(unsigned* ctr, unsigned target) {
  __syncthreads();
  if (threadIdx.x == 0) {
    __threadfence();
    atomicAdd(ctr, 1u);
    while (atomicAdd(ctr, 0u) < target) __builtin_amdgcn_s_sleep(8);
    __threadfence();
  }
  __syncthreads();
}

// exact 32nd-largest + softmax stats over 1024 values (block-local, 256 thr)
DEV void topk_stats(const float* __restrict__ simg, int tid, int lane, int w,
                    unsigned* hist, unsigned* wtot, float* red,
                    unsigned* sh_pref, int* sh_k, float* out) {
  const float4 fv = *(const float4*)(simg + tid * 4);
  float f[4] = {fv.x, fv.y, fv.z, fv.w};
  unsigned u[4];
#pragma unroll
  for (int i = 0; i < 4; i++) {
    unsigned bb = __float_as_uint(f[i]);
    u[i] = (bb & 0x80000000u) ? ~bb : (bb | 0x80000000u);
  }
  float mx = fmaxf(fmaxf(f[0], f[1]), fmaxf(f[2], f[3]));
  mx = wave_max(mx);
  if (lane == 0) red[w] = mx;
  if (tid == 0) { *sh_pref = 0u; *sh_k = 32; }
  __syncthreads();
  float maxv = fmaxf(fmaxf(red[0], red[1]), fmaxf(red[2], red[3]));
#pragma unroll 1
  for (int pass = 0; pass < 4; pass++) {
    int shift = 24 - pass * 8;
    unsigned pref = *sh_pref;
    unsigned kk = (unsigned)*sh_k;
    unsigned pm = (pass == 0) ? 0u : (0xFFFFFFFFu << (shift + 8));
    hist[tid] = 0u;
    __syncthreads();
#pragma unroll
    for (int i = 0; i < 4; i++)
      if ((u[i] & pm) == pref) atomicAdd(&hist[(u[i] >> shift) & 255], 1u);
    __syncthreads();
    unsigned cnt = hist[tid];
    unsigned s = cnt;
#pragma unroll
    for (int off = 1; off < 64; off <<= 1) {
      unsigned t2 = __shfl_down(s, off, 64);
      if (lane + off < 64) s += t2;
    }
    if (lane == 0) wtot[w] = s;
    __syncthreads();
    unsigned ge = s;
    for (int w2 = w + 1; w2 < 4; w2++) ge += wtot[w2];
    unsigned gt = ge - cnt;
    if (ge >= kk && gt < kk) { *sh_pref = pref | ((unsigned)tid << shift); *sh_k = (int)(kk - gt); }
    __syncthreads();
  }
  unsigned ku = *sh_pref;
  float kth = __uint_as_float((ku & 0x80000000u) ? (ku & 0x7FFFFFFFu) : ~ku);
  float se = 0.f;
#pragma unroll
  for (int i = 0; i < 4; i++)
    if (f[i] >= kth) se += expf(f[i] - maxv);
  se = wave_sum(se);
  if (lane == 0) red[w] = se;
  __syncthreads();
  if (tid == 0) {
    out[0] = kth; out[1] = maxv; out[2] = 1.f / (red[0] + red[1] + red[2] + red[3]);
  }
  __syncthreads();
}

__global__ void __launch_bounds__(256) k_scan(ScanArgs a) {
  float* ws = a.ws;
  float* mem = ws + OFF_MEM;
  unsigned* syncb = (unsigned*)(ws + OFF_SYNC);
  float* rvbuf = ws + OFF_RVBUF;   // [2][4][512]
  float* rpart = ws + OFF_RPART;   // [2][4][4][4][128] parity,b,h,g,d
  float* keyinv = ws + OFF_KEYINV; // [2][16]
  float* ifc = ws + OFF_IFACE;     // [4][2176]
  float* simr = ws + OFF_SIMR;     // [16][1024]
  float* simw = ws + OFF_SIMW;
  float* RVA = ws + OFF_RSEQ;      // [4][128][512] rv_after(t)
  const float* preif = ws + OFF_PREIF;

  const int tid = threadIdx.x;
  const int blk = blockIdx.x;      // 64
  const int b = blk >> 4, h = (blk >> 2) & 3, g = blk & 3;
  const int bh = b * 4 + h;
  const int lane = tid & 63, w = tid >> 6;
  unsigned* BC = syncb + b * 64;
  unsigned* GC2 = syncb + 256 + bh * 64;
  unsigned* GC3 = syncb + 1280 + bh * 64;

  __shared__ float rvs[512];
  __shared__ float pA[128];
  __shared__ float keysL[512];     // rk|wk|wv|er (128 each, head slice)
  __shared__ float simL[512];      // own slots: r[256], w[256]
  __shared__ float rpw[4][128];
  __shared__ unsigned histL[256];
  __shared__ unsigned wtotL[4];
  __shared__ float redL[4];
  __shared__ float statsL[8];
  __shared__ unsigned sh_pref;
  __shared__ int sh_k;
  __shared__ float agL;

  const float beta_r = fminf(fmaxf(log1pf(expf(a.betar[0])), 1.f), 20.f);
  const float beta_w = fminf(fmaxf(log1pf(expf(a.betaw[0])), 1.f), 20.f);

  for (int t = a.t0; t < a.t1; ++t) {
    if (t > a.t0) barrier_at(BC, (unsigned)(t - a.sgi) * 16u);

    // -------- Phase A: rv reduce (all blocks), iface GEMV (own 128 cols) ----
    {
      const float* rvold = rvbuf + (size_t)(t & 1) * 2048 + b * 512;
      const float* rp = rpart + (size_t)(((t & 1) ^ 1)) * 8192 + (size_t)b * 4 * 4 * 128;
#pragma unroll
      for (int p = 0; p < 2; p++) {
        int i = tid + p * 256;
        int hh = i >> 7, d = i & 127;
        const float* rph = rp + hh * 512 + d;
        rvs[i] = rvold[i] + rph[0] + rph[128] + rph[256] + rph[384];
      }
      __syncthreads();
      if (h == 0 && g == 0) {
        float* rvnew = rvbuf + (size_t)(((t & 1) ^ 1)) * 2048 + b * 512;
#pragma unroll
        for (int p = 0; p < 2; p++) {
          int i = tid + p * 256;
          rvnew[i] = rvs[i];
          if (t >= 1) RVA[((size_t)b * 128 + (t - 1)) * 512 + i] = rvs[i];
        }
      }
      // GEMV: 128 cols (c0 = g*512 + h*128), 2 threads per col split over k
      int jloc = tid & 127, kh = tid >> 7;
      int col = g * 512 + h * 128 + jloc;
      const float* wp = a.Wif + (size_t)(512 + kh * 256) * 2049 + col;
      float acc = 0.f;
#pragma unroll 4
      for (int k = 0; k < 256; k++)
        acc = fmaf(rvs[kh * 256 + k], wp[(size_t)k * 2049], acc);
      if (tid >= 128) pA[jloc] = acc;
      __syncthreads();
      float val = 0.f;
      if (tid < 128) {
        val = preif[((size_t)b * 128 + t) * 2049 + col] + acc + pA[jloc];
        ifc[b * 2176 + col] = (g == 3) ? sigm_f(val) : val;
      }
      if (g < 2) {   // key norms: g0 -> rk_h, g1 -> wk_h
        float sq = (tid < 128) ? val * val : 0.f;
        sq = wave_sum(sq);
        if (lane == 0) redL[w] = sq;
        __syncthreads();
        if (tid == 0)
          keyinv[g * 16 + bh] = 1.f / sqrtf(redL[0] + redL[1] + redL[2] + redL[3] + 1e-8f);
      }
      if (g == 3) {  // add-gate col 2048
        float pa = rvs[tid] * a.Wif[(size_t)(512 + tid) * 2049 + 2048]
                 + rvs[tid + 256] * a.Wif[(size_t)(768 + tid) * 2049 + 2048];
        pa = wave_sum(pa);
        if (lane == 0) redL[w] = pa;
        __syncthreads();
        if (tid == 0) {
          float tot = preif[((size_t)b * 128 + t) * 2049 + 2048]
                    + redL[0] + redL[1] + redL[2] + redL[3];
          ifc[b * 2176 + 2048] = sigm_f(tot);
        }
      }
    }
    barrier_at(GC2, (unsigned)(t + 1) * 4u);

    // -------- Phase B: sims for own 256 slots --------------------------------
    {
      int ib = b * 2176;
      if (tid < 128) {
        keysL[tid]       = ifc[ib + h * 128 + tid];            // rk
        keysL[256 + tid] = ifc[ib + 1024 + h * 128 + tid];     // wv
      } else {
        int j = tid - 128;
        keysL[128 + j] = ifc[ib + 512 + h * 128 + j];          // wk
        keysL[384 + j] = ifc[ib + 1536 + h * 128 + j];         // er (sigmoided)
      }
      if (tid == 0) agL = ifc[ib + 2048];
      float krF = keyinv[bh] * beta_r;
      float kwF = keyinv[16 + bh] * beta_w;
      __syncthreads();
      int q = tid & 3, swi = tid >> 2;
#pragma unroll 1
      for (int p = 0; p < 4; p++) {
        int sp = p * 64 + swi;
        int s = g * 256 + sp;
        const float* mrow = mem + ((size_t)(b * 1024 + s)) * 512 + h * 128 + q * 32;
        float dr = 0.f, dw = 0.f, ss = 0.f;
#pragma unroll
        for (int j = 0; j < 8; j++) {
          float4 mv = *(const float4*)(mrow + j * 4);
          float4 rk4 = *(const float4*)&keysL[q * 32 + j * 4];
          float4 wk4 = *(const float4*)&keysL[128 + q * 32 + j * 4];
          ss = fmaf(mv.x, mv.x, ss); ss = fmaf(mv.y, mv.y, ss);
          ss = fmaf(mv.z, mv.z, ss); ss = fmaf(mv.w, mv.w, ss);
          dr = fmaf(mv.x, rk4.x, dr); dr = fmaf(mv.y, rk4.y, dr);
          dr = fmaf(mv.z, rk4.z, dr); dr = fmaf(mv.w, rk4.w, dr);
          dw = fmaf(mv.x, wk4.x, dw); dw = fmaf(mv.y, wk4.y, dw);
          dw = fmaf(mv.z, wk4.z, dw); dw = fmaf(mv.w, wk4.w, dw);
        }
        dr += __shfl_xor(dr, 1, 64); dr += __shfl_xor(dr, 2, 64);
        dw += __shfl_xor(dw, 1, 64); dw += __shfl_xor(dw, 2, 64);
        ss += __shfl_xor(ss, 1, 64); ss += __shfl_xor(ss, 2, 64);
        if (q == 0) {
          float invs = 1.f / sqrtf(ss + 1e-8f);
          float s_r = dr * invs * krF, s_w = dw * invs * kwF;
          simL[sp] = s_r; simL[256 + sp] = s_w;
          simr[(size_t)bh * 1024 + s] = s_r;
          simw[(size_t)bh * 1024 + s] = s_w;
        }
      }
    }
    barrier_at(GC3, (unsigned)(t + 1) * 4u);

    // -------- Phase C: block-redundant exact top-32 stats (r then w) --------
    topk_stats(simr + (size_t)bh * 1024, tid, lane, w, histL, wtotL, redL,
               &sh_pref, &sh_k, statsL);
    topk_stats(simw + (size_t)bh * 1024, tid, lane, w, histL, wtotL, redL,
               &sh_pref, &sh_k, statsL + 4);

    // -------- Phase D: mem update + read partial over own slots -------------
    {
      float kr = statsL[0], mr = statsL[1], ir = statsL[2];
      float kw = statsL[4], mw = statsL[5], iw = statsL[6];
      float ag = agL;
      int q = tid & 3, swi = tid >> 2;
      float racc[32];
#pragma unroll
      for (int i = 0; i < 32; i++) racc[i] = 0.f;
#pragma unroll 1
      for (int p = 0; p < 4; p++) {
        int sp = p * 64 + swi;
        int s = g * 256 + sp;
        float sr = simL[sp], sw2 = simL[256 + sp];
        float wr = (sr >= kr) ? expf(sr - mr) * ir : 0.f;
        float ww = (sw2 >= kw) ? expf(sw2 - mw) * iw : 0.f;
        float agw = ag * ww;
        float* mrow = mem + ((size_t)(b * 1024 + s)) * 512 + h * 128 + q * 32;
#pragma unroll
        for (int j = 0; j < 8; j++) {
          float4 ov = *(const float4*)(mrow + j * 4);
          float4 er4 = *(const float4*)&keysL[384 + q * 32 + j * 4];
          float4 wv4 = *(const float4*)&keysL[256 + q * 32 + j * 4];
          racc[j * 4 + 0] = fmaf(wr, ov.x, racc[j * 4 + 0]);
          racc[j * 4 + 1] = fmaf(wr, ov.y, racc[j * 4 + 1]);
          racc[j * 4 + 2] = fmaf(wr, ov.z, racc[j * 4 + 2]);
          racc[j * 4 + 3] = fmaf(wr, ov.w, racc[j * 4 + 3]);
          float4 nv;
          nv.x = (ov.x * (1.f - ww * er4.x) + agw * wv4.x) * 0.99f;
          nv.y = (ov.y * (1.f - ww * er4.y) + agw * wv4.y) * 0.99f;
          nv.z = (ov.z * (1.f - ww * er4.z) + agw * wv4.z) * 0.99f;
          nv.w = (ov.w * (1.f - ww * er4.w) + agw * wv4.w) * 0.99f;
          *(float4*)(mrow + j * 4) = nv;
        }
      }
      // reduce racc across the 16 same-q lanes of each wave
#pragma unroll
      for (int m = 4; m <= 32; m <<= 1)
#pragma unroll
        for (int i = 0; i < 32; i++) racc[i] += __shfl_xor(racc[i], m, 64);
      if (lane < 4)
#pragma unroll
        for (int i = 0; i < 32; i++) rpw[w][lane * 32 + i] = racc[i];
      __syncthreads();
      if (tid < 128) {
        float v = rpw[0][tid] + rpw[1][tid] + rpw[2][tid] + rpw[3][tid];
        rpart[(size_t)(t & 1) * 8192 + ((size_t)(bh * 4 + g)) * 128 + tid] = v;
      }
      __syncthreads();
    }
  }

  // final rv_after(127) -> RVA[127]
  if (a.t1 == 128) {
    barrier_at(BC, (unsigned)(128 - a.sgi) * 16u);
    if (h == 0 && g == 0) {
      const float* rvold = rvbuf + 0 * 2048 + b * 512;   // parity of t=128
      const float* rp = rpart + (size_t)1 * 8192 + (size_t)b * 4 * 4 * 128;
#pragma unroll
      for (int p = 0; p < 2; p++) {
        int i = tid + p * 256;
        int hh = i >> 7, d = i & 127;
        const float* rph = rp + hh * 512 + d;
        RVA[((size_t)b * 128 + 127) * 512 + i] =
            rvold[i] + rph[0] + rph[128] + rph[256] + rph[384];
      }
    }
  }
}

// ---------------- concat [hs, RVA[t-1]] -> ctrl (logits use PRE-update rv) --
__global__ void __launch_bounds__(256) k_concat(const float* __restrict__ hs,
                                                const float* __restrict__ rva,
                                                float* __restrict__ ctrl) {
  int bt = blockIdx.x;
  int t = bt & 127;
  int tid = threadIdx.x;
#pragma unroll
  for (int p = 0; p < 4; p++) {
    int i = tid + p * 256;
    float v;
    if (i < 512) v = hs[(size_t)bt * 512 + i];
    else v = (t == 0) ? 0.f : rva[(size_t)(bt - 1) * 512 + (i - 512)];
    ctrl[(size_t)bt * 1024 + i] = v;
  }
}

// ---------------- host ----------------
extern "C" void kernel_launch(void* const* d_in, const int* in_sizes, int n_in,
                              void* d_out, int out_size, void* d_ws, size_t ws_size,
                              hipStream_t stream) {
  (void)in_sizes; (void)n_in; (void)out_size; (void)ws_size;
  const int* tok = (const int*)d_in[0];
  const float* emb = (const float*)d_in[1];
  const float* pos = (const float*)d_in[2];
  const float* Wqkv = (const float*)d_in[3];
  const float* Wo = (const float*)d_in[4];
  const float* W1 = (const float*)d_in[5];
  const float* W2 = (const float*)d_in[6];
  const float* Wif = (const float*)d_in[7];
  const float* bif = (const float*)d_in[8];
  const float* Wlg = (const float*)d_in[9];
  const float* br = (const float*)d_in[10];
  const float* bw = (const float*)d_in[11];
  const float* Whall = (const float*)d_in[12];
  const float* bhall = (const float*)d_in[13];
  const float* Sq = (const float*)d_in[14];
  const float* Sk = (const float*)d_in[15];
  const float* Sv = (const float*)d_in[16];
  const float* So = (const float*)d_in[17];
  const float* SW1 = (const float*)d_in[18];
  const float* SW2 = (const float*)d_in[19];
  float* ws = (float*)d_ws;
  float* out = (float*)d_out;

  float* mem = ws + OFF_MEM;
  float* rseq = ws + OFF_RSEQ;
  float* hs = ws + OFF_HS;
  float* preif = ws + OFF_PREIF;
  float* bufA = ws + OFF_BUFA;
  float* bufB = ws + OFF_BUFB;
  float* bufC = ws + OFF_BUFC;
  float* bufD = ws + OFF_BUFD;
  float* ctrl = bufA;  // reused after synthesize epochs are done

  // zero: mem + sync counters + rvbuf + rpart (contiguous region)
  hipMemsetAsync(d_ws, 0, (OFF_RPART + 16384) * sizeof(float), stream);

  // ---- transformer ----
  k_embed<<<512, 256, 0, stream>>>(tok, emb, pos, hs);
  for (int l = 0; l < 2; l++) {
    k_ln<<<512, 256, 0, stream>>>(hs, bufA);
    k_gemm<0, 0, 0, 0><<<dim3(24, 8), 256, 0, stream>>>(
        bufA, Wqkv + (size_t)l * 512 * 1536, nullptr, bufB, 512, 1536, 512);
    k_attn<<<4096, 128, 0, stream>>>(bufB, bufC);
    k_gemm<0, 0, 1, 0><<<dim3(8, 8), 256, 0, stream>>>(
        bufC, Wo + (size_t)l * 512 * 512, nullptr, hs, 512, 512, 512);
    k_ln<<<512, 256, 0, stream>>>(hs, bufA);
    k_gemm<0, 1, 0, 0><<<dim3(16, 8), 256, 0, stream>>>(
        bufA, W1 + (size_t)l * 512 * 1024, nullptr, bufB, 512, 1024, 512);
    k_gemm<0, 0, 1, 0><<<dim3(8, 8), 256, 0, stream>>>(
        bufB, W2 + (size_t)l * 1024 * 512, nullptr, hs, 512, 512, 1024);
  }
  // pre_iface = hs @ Wif[:512] + b_iface
  k_gemm<1, 0, 0, 1><<<dim3(33, 8), 256, 0, stream>>>(hs, Wif, bif, preif, 512, 2049, 512);

  // ---- scan: 9 cooperative segments, synthesize after first 8 ----
  const int segs[10] = {0, 1, 17, 33, 49, 65, 81, 97, 113, 128};
  for (int sgi = 0; sgi < 9; sgi++) {
    ScanArgs sa{ws, Wif, br, bw, segs[sgi], segs[sgi + 1], sgi};
    void* kp[] = {&sa};
    hipLaunchCooperativeKernel((void*)k_scan, dim3(64), dim3(256), kp, 0, stream);
    if (sgi < 8) {
      k_ln<<<4096, 256, 0, stream>>>(mem, bufA);
      k_gemm<0, 0, 0, 0><<<dim3(8, 64), 256, 0, stream>>>(bufA, Sq, nullptr, bufB, 4096, 512, 512);
      k_gemm<0, 0, 0, 0><<<dim3(8, 64), 256, 0, stream>>>(bufA, Sk, nullptr, bufC, 4096, 512, 512);
      k_gemm<0, 0, 0, 0><<<dim3(8, 64), 256, 0, stream>>>(bufA, Sv, nullptr, bufD, 4096, 512, 512);
      k_sattn<<<512, 256, 0, stream>>>(bufB, bufC, bufD, bufA);
      k_gemm<0, 0, 1, 0><<<dim3(8, 64), 256, 0, stream>>>(bufA, So, nullptr, mem, 4096, 512, 512);
      k_ln<<<4096, 256, 0, stream>>>(mem, bufA);
      k_gemm<0, 1, 0, 0><<<dim3(2, 64), 256, 0, stream>>>(bufA, SW1, nullptr, bufB, 4096, 128, 512);
      k_gemm<0, 0, 1, 0><<<dim3(8, 64), 256, 0, stream>>>(bufB, SW2, nullptr, mem, 4096, 512, 128);
    }
  }

  // ---- deferred outputs ----
  k_concat<<<512, 256, 0, stream>>>(hs, rseq, ctrl);
  k_gemm<0, 0, 0, 0><<<dim3(500, 8), 256, 0, stream>>>(ctrl, Wlg, nullptr, out, 512, 32000, 1024);
  k_gemm<1, 0, 0, 0><<<dim3(8, 8), 256, 0, stream>>>(
      rseq, Whall, bhall, out + (size_t)512 * 32000, 512, 512, 512);
}